// Round 6
// baseline (361.394 us; speedup 1.0000x reference)
//
#include <hip/hip_runtime.h>
#include <cstddef>
#include <cstdint>

#define B 32
#define T 1024
#define J 128
#define H 1024

typedef unsigned short ushort_t;
typedef __attribute__((ext_vector_type(8))) short bf16x8;
typedef __attribute__((ext_vector_type(4))) float f32x4;
typedef __attribute__((ext_vector_type(4))) float fvec4;
typedef __attribute__((ext_vector_type(2))) unsigned int uvec2;
typedef __attribute__((ext_vector_type(4))) unsigned int uvec4;

__device__ __forceinline__ unsigned short f2bf(float f) {
    union { float f; unsigned u; } v;
    v.f = f;
    return (unsigned short)((v.u + 0x7FFFu + ((v.u >> 16) & 1u)) >> 16);
}
__device__ __forceinline__ float bf2f(unsigned short s) {
    union { unsigned u; float f; } v;
    v.u = ((unsigned)s) << 16;
    return v.f;
}

// nontemporal helpers via native ext-vector types (HIP_vector_type rejected)
__device__ __forceinline__ float4 nt_ld4(const float* p) {
    fvec4 r = __builtin_nontemporal_load((const fvec4*)p);
    return make_float4(r.x, r.y, r.z, r.w);
}
__device__ __forceinline__ uint2 nt_ld2u(const ushort_t* p) {
    uvec2 r = __builtin_nontemporal_load((const uvec2*)p);
    return make_uint2(r.x, r.y);
}
__device__ __forceinline__ void nt_st4(float* p, float4 v) {
    fvec4 t = {v.x, v.y, v.z, v.w};
    __builtin_nontemporal_store(t, (fvec4*)p);
}
__device__ __forceinline__ void nt_st4u(ushort_t* p, uint4 v) {
    uvec4 t = {v.x, v.y, v.z, v.w};
    __builtin_nontemporal_store(t, (uvec4*)p);
}

// ---------------------------------------------------------------------------
// k_uprep: u2_bf[b,j,d] = bf16(wh[d] + wm[d]*u), uT_bf[b,d,j] = bf16(u),
// fused partial dot pdot[(b*J+j)*16 + dtile] = sum u*wu
// ---------------------------------------------------------------------------
__global__ __launch_bounds__(256) void k_uprep(const float* __restrict__ u,
                                               const float* __restrict__ w,
                                               ushort_t* __restrict__ u2,
                                               ushort_t* __restrict__ uT,
                                               float* __restrict__ pdot) {
    int b = blockIdx.z, j0 = blockIdx.y * 64, d0 = blockIdx.x * 64;
    __shared__ ushort_t tile[64][72];
    int tid = threadIdx.x;
    int jr = tid >> 2, c0 = (tid & 3) * 16;
    const float* wh = w;
    const float* wu = w + H;
    const float* wm = w + 2 * H;
    size_t src = ((size_t)(b << 7) + j0 + jr) * H + d0 + c0;
    union { ushort_t us[16]; uint4 v[2]; } o;
    float dot = 0.0f;
#pragma unroll
    for (int i = 0; i < 16; i += 4) {
        float4 x = nt_ld4(&u[src + i]);  // u read exactly once -> stream
        const float* xp = &x.x;
#pragma unroll
        for (int k = 0; k < 4; ++k) {
            int d = d0 + c0 + i + k;
            float uu = xp[k];
            o.us[i + k] = f2bf(wh[d] + wm[d] * uu);
            tile[jr][c0 + i + k] = f2bf(uu);
            dot += uu * wu[d];
        }
    }
    *(uint4*)&u2[src] = o.v[0];      // reused by gemm1 -> keep cached
    *(uint4*)&u2[src + 8] = o.v[1];
    dot += __shfl_xor(dot, 1);
    dot += __shfl_xor(dot, 2);
    if ((tid & 3) == 0)
        pdot[((size_t)(b << 7) + j0 + jr) * 16 + blockIdx.x] = dot;
    __syncthreads();
    int dr = tid >> 2, jc0 = (tid & 3) * 16;
    union { ushort_t us[16]; uint4 v[2]; } t2;
#pragma unroll
    for (int i = 0; i < 16; ++i) t2.us[i] = tile[jc0 + i][dr];
    size_t dst = ((size_t)(b << 10) + d0 + dr) * J + j0 + jc0;
    *(uint4*)&uT[dst] = t2.v[0];     // reused by gemm2g -> keep cached
    *(uint4*)&uT[dst + 8] = t2.v[1];
}

// ---------------------------------------------------------------------------
// k_sured: suB[col] = sum_16 pdot[col][r] + b0
// ---------------------------------------------------------------------------
__global__ __launch_bounds__(256) void k_sured(const float* __restrict__ pdot,
                                               const float* __restrict__ bscal,
                                               float* __restrict__ suB) {
    int col = blockIdx.x * 256 + threadIdx.x;
    float s = 0.0f;
#pragma unroll
    for (int r = 0; r < 16; ++r) s += pdot[(size_t)col * 16 + r];
    suB[col] = s + bscal[0];
}

// ---------------------------------------------------------------------------
// k_gemm1: S_bf = bf16(h @ u2^T + suB); side-writes hbf = bf16(h) (nt).
// 64x128 tile, BK=64, 256 thr (4 waves 2x2), 512 blocks = 2 blocks/CU.
// XCD-pinned: 4 batches per XCD for u2 L2 reuse.
// ---------------------------------------------------------------------------
__global__ __launch_bounds__(256) void k_gemm1(const float* __restrict__ h,
                                               const ushort_t* __restrict__ u2,
                                               const float* __restrict__ suB,
                                               ushort_t* __restrict__ Sb,
                                               ushort_t* __restrict__ hbf,
                                               float* __restrict__ Mrow,
                                               float* __restrict__ pcm,
                                               float* __restrict__ pcs) {
    const int lid = blockIdx.x;
    const int xcd = lid & 7;
    const int seq = lid >> 3;          // 0..63
    const int b = xcd * 4 + (seq >> 4);
    const int tt = seq & 15;
    const int t0 = tt * 64;
    __shared__ ushort_t As[64 * 64];
    __shared__ ushort_t Bs[128 * 64];
    __shared__ float rm_red[2][64];
    __shared__ float cm_red[2][128];
    __shared__ float cs_red[2][128];
    const int tid = threadIdx.x;
    const int lane = tid & 63, wid = tid >> 6;
    const int wr = wid >> 1, wc = wid & 1;

    f32x4 acc[2][4] = {};

    const int srow = tid >> 3;         // 0..31
    const int su_ = tid & 7;
    const int r7 = srow & 7;
    const int kk = (su_ ^ r7) << 3;    // f32 element offset (A)
    const int cb = (su_ ^ r7) << 4;    // byte offset (B)

    for (int k0 = 0; k0 < H; k0 += 64) {
        // stage A: h f32 -> bf16 (2 passes of 32 rows), side-write hbf
#pragma unroll
        for (int p = 0; p < 2; ++p) {
            int row = srow + p * 32;
            size_t hoff = ((size_t)(b << 10) + t0 + row) * H + k0 + kk;
            float4 x = nt_ld4(h + hoff);
            float4 y = nt_ld4(h + hoff + 4);
            union { ushort_t us[8]; uint4 v; } pk;
            pk.us[0] = f2bf(x.x); pk.us[1] = f2bf(x.y);
            pk.us[2] = f2bf(x.z); pk.us[3] = f2bf(x.w);
            pk.us[4] = f2bf(y.x); pk.us[5] = f2bf(y.y);
            pk.us[6] = f2bf(y.z); pk.us[7] = f2bf(y.w);
            *(uint4*)&As[row * 64 + (su_ << 3)] = pk.v;
            nt_st4u(&hbf[hoff], pk.v);  // stream: consumed by later kernels
        }
        // stage B: u2 bf16 (4 passes of 32 rows), pre-swizzled source
#pragma unroll
        for (int p = 0; p < 4; ++p) {
            int row = srow + p * 32;
            uint4 val = *(const uint4*)((const char*)u2 +
                        (((size_t)(b << 7) + row) * H + k0) * 2 + cb);
            *(uint4*)&Bs[row * 64 + (su_ << 3)] = val;
        }
        __syncthreads();
#pragma unroll
        for (int ks = 0; ks < 2; ++ks) {
            bf16x8 af[2], bfr[4];
            int cbyte = ks * 64 + ((lane >> 4) << 4);
#pragma unroll
            for (int mi = 0; mi < 2; ++mi) {
                int row = wr * 32 + mi * 16 + (lane & 15);
                af[mi] = *(const bf16x8*)&As[row * 64 + ((cbyte ^ ((row & 7) << 4)) >> 1)];
            }
#pragma unroll
            for (int nj = 0; nj < 4; ++nj) {
                int row = wc * 64 + nj * 16 + (lane & 15);
                bfr[nj] = *(const bf16x8*)&Bs[row * 64 + ((cbyte ^ ((row & 7) << 4)) >> 1)];
            }
#pragma unroll
            for (int mi = 0; mi < 2; ++mi)
#pragma unroll
                for (int nj = 0; nj < 4; ++nj)
                    acc[mi][nj] = __builtin_amdgcn_mfma_f32_16x16x32_bf16(
                        af[mi], bfr[nj], acc[mi][nj], 0, 0, 0);
        }
        __syncthreads();
    }

    // epilogue: +suB, bf16 S store, row-max + column (max,sumexp) partials
    const int jbase = wc * 64 + (lane & 15);
    float rowmax[2][4];
#pragma unroll
    for (int mi = 0; mi < 2; ++mi)
#pragma unroll
        for (int r = 0; r < 4; ++r) rowmax[mi][r] = -INFINITY;
    float cmv[4], csv[4];
#pragma unroll
    for (int nj = 0; nj < 4; ++nj) {
        float su_v = suB[(b << 7) + jbase + nj * 16];
        float tmp[8];
        float cm = -INFINITY;
#pragma unroll
        for (int mi = 0; mi < 2; ++mi)
#pragma unroll
            for (int r = 0; r < 4; ++r) {
                float sv = acc[mi][nj][r] + su_v;
                unsigned short sb = f2bf(sv);
                float svb = bf2f(sb);
                int t = t0 + wr * 32 + mi * 16 + ((lane >> 4) << 2) + r;
                Sb[((size_t)(b << 10) + t) * J + jbase + nj * 16] = sb;
                tmp[mi * 4 + r] = svb;
                cm = fmaxf(cm, svb);
                rowmax[mi][r] = fmaxf(rowmax[mi][r], svb);
            }
        float cs = 0.0f;
#pragma unroll
        for (int i = 0; i < 8; ++i) cs += __expf(tmp[i] - cm);
        cmv[nj] = cm;
        csv[nj] = cs;
    }
#pragma unroll
    for (int mi = 0; mi < 2; ++mi)
#pragma unroll
        for (int r = 0; r < 4; ++r) {
            float v = rowmax[mi][r];
#pragma unroll
            for (int off = 1; off < 16; off <<= 1) v = fmaxf(v, __shfl_xor(v, off));
            if ((lane & 15) == 0) {
                int row = wr * 32 + mi * 16 + ((lane >> 4) << 2) + r;
                rm_red[wc][row] = v;
            }
        }
#pragma unroll
    for (int nj = 0; nj < 4; ++nj) {
        float cm = cmv[nj], cs = csv[nj];
#pragma unroll
        for (int off = 16; off < 64; off <<= 1) {
            float om = __shfl_xor(cm, off);
            float os = __shfl_xor(cs, off);
            float nm = fmaxf(cm, om);
            cs = cs * __expf(cm - nm) + os * __expf(om - nm);
            cm = nm;
        }
        if (lane < 16) {
            cm_red[wr][wc * 64 + nj * 16 + lane] = cm;
            cs_red[wr][wc * 64 + nj * 16 + lane] = cs;
        }
    }
    __syncthreads();
    if (tid < 64) {
        Mrow[(b << 10) + t0 + tid] = fmaxf(rm_red[0][tid], rm_red[1][tid]);
    } else if (tid < 192) {
        int j = tid - 64;
        float m = cm_red[0][j], s = cs_red[0][j];
        float m2 = cm_red[1][j], s2 = cs_red[1][j];
        float nm = fmaxf(m, m2);
        s = s * __expf(m - nm) + s2 * __expf(m2 - nm);
        int col = (b << 7) + j;
        pcm[col * 16 + tt] = nm;
        pcs[col * 16 + tt] = s;
    }
}

// ---------------------------------------------------------------------------
// k_q2c_part: self-contained bt softmax stats from Mrow, then partial
// q2c over a 64-row t-chunk reading hbf (nt). grid (16, B), 256 thr.
// ---------------------------------------------------------------------------
__global__ __launch_bounds__(256) void k_q2c_part(const ushort_t* __restrict__ hbf,
                                                  const float* __restrict__ Mrow,
                                                  float* __restrict__ part) {
    int tc = blockIdx.x, b = blockIdx.y;
    int tid = threadIdx.x;
    __shared__ float red[256];
    __shared__ float wbt[64];
    const float* mr = Mrow + (b << 10);
    float m = fmaxf(fmaxf(mr[tid], mr[tid + 256]), fmaxf(mr[tid + 512], mr[tid + 768]));
    red[tid] = m;
    __syncthreads();
    for (int o = 128; o; o >>= 1) {
        if (tid < o) red[tid] = fmaxf(red[tid], red[tid + o]);
        __syncthreads();
    }
    m = red[0];
    __syncthreads();
    float s = 0.0f;
    for (int t = tid; t < T; t += 256) s += __expf(mr[t] - m);
    red[tid] = s;
    __syncthreads();
    for (int o = 128; o; o >>= 1) {
        if (tid < o) red[tid] += red[tid + o];
        __syncthreads();
    }
    float binv = 1.0f / red[0];
    if (tid < 64) wbt[tid] = __expf(mr[tc * 64 + tid] - m) * binv;
    __syncthreads();

    int dd = tid * 4;
    float acc0 = 0.f, acc1 = 0.f, acc2 = 0.f, acc3 = 0.f;
#pragma unroll 4
    for (int i = 0; i < 64; ++i) {
        int t = tc * 64 + i;
        uint2 v = nt_ld2u(&hbf[((size_t)(b << 10) + t) * H + dd]);
        const ushort_t* us = (const ushort_t*)&v;
        float wv = wbt[i];
        acc0 += wv * bf2f(us[0]);
        acc1 += wv * bf2f(us[1]);
        acc2 += wv * bf2f(us[2]);
        acc3 += wv * bf2f(us[3]);
    }
    size_t pb = (((size_t)b * 16 + tc) << 10) + dd;
    *(float4*)&part[pb] = make_float4(acc0, acc1, acc2, acc3);
}

// ---------------------------------------------------------------------------
// k_gemm2g: prologue reduces (pcm,pcs)->cmax/cinv and qpart->q2c into LDS;
// stages P with fused softmax normalize; c2q = P @ u via MFMA (A=uT rows=d,
// B=P cols=t); G written with nontemporal float4 stores. XCD-pinned.
// ---------------------------------------------------------------------------
__global__ __launch_bounds__(256) void k_gemm2g(const ushort_t* __restrict__ Sb,
                                                const ushort_t* __restrict__ uT,
                                                const ushort_t* __restrict__ hbf,
                                                const float* __restrict__ pcm,
                                                const float* __restrict__ pcs,
                                                const float* __restrict__ qpart,
                                                float* __restrict__ G) {
    const int lid = blockIdx.x;
    const int seq = lid >> 3;
    const int b = (lid & 7) * 4 + (seq >> 6);
    const int inner = seq & 63;
    const int d0 = (inner >> 3) * 128;
    const int t0 = (inner & 7) * 128;
    __shared__ ushort_t Ps[128 * 64];
    __shared__ ushort_t Us[128 * 64];
    __shared__ float cmaxs[128], cinvs[128], q2cs[128];
    const int tid = threadIdx.x;
    const int lane = tid & 63, wid = tid >> 6;
    const int wd = wid >> 1, wt = wid & 1;

    if (tid < 128) {
        int col = (b << 7) + tid;
        float m = -INFINITY, s = 0.0f;
#pragma unroll
        for (int r = 0; r < 16; ++r) {
            float m2 = pcm[col * 16 + r], s2 = pcs[col * 16 + r];
            float nm = fmaxf(m, m2);
            s = s * __expf(m - nm) + s2 * __expf(m2 - nm);
            m = nm;
        }
        cmaxs[tid] = m;
        cinvs[tid] = 1.0f / s;
    } else {
        int d = d0 + tid - 128;
        float a = 0.0f;
#pragma unroll
        for (int tc = 0; tc < 16; ++tc)
            a += qpart[(((size_t)b * 16 + tc) << 10) + d];
        q2cs[tid - 128] = a;
    }
    __syncthreads();

    f32x4 acc[4][4] = {};
    for (int j0 = 0; j0 < J; j0 += 64) {
#pragma unroll
        for (int w = 0; w < 4; ++w) {
            int row = w * 32 + (tid >> 3);
            int u_ = tid & 7;
            int cb = (u_ ^ ((tid >> 3) & 7)) << 4;
            uint4 va = *(const uint4*)((const char*)Sb +
                       (((size_t)(b << 10) + t0 + row) * J + j0) * 2 + cb);
            int jb = j0 + (cb >> 1);
            union { ushort_t us[8]; uint4 v; } pp;
            pp.v = va;
#pragma unroll
            for (int i = 0; i < 8; ++i)
                pp.us[i] = f2bf(__expf(bf2f(pp.us[i]) - cmaxs[jb + i]) * cinvs[jb + i]);
            *(uint4*)&Ps[row * 64 + (u_ << 3)] = pp.v;
            uint4 vb = *(const uint4*)((const char*)uT +
                       (((size_t)(b << 10) + d0 + row) * J + j0) * 2 + cb);
            *(uint4*)&Us[row * 64 + (u_ << 3)] = vb;
        }
        __syncthreads();
#pragma unroll
        for (int ks = 0; ks < 2; ++ks) {
            bf16x8 af[4], bfr[4];
            int cbyte = ks * 64 + ((lane >> 4) << 4);
#pragma unroll
            for (int mi = 0; mi < 4; ++mi) {
                int row = wd * 64 + mi * 16 + (lane & 15);
                af[mi] = *(const bf16x8*)&Us[row * 64 + ((cbyte ^ ((row & 7) << 4)) >> 1)];
            }
#pragma unroll
            for (int nj = 0; nj < 4; ++nj) {
                int row = wt * 64 + nj * 16 + (lane & 15);
                bfr[nj] = *(const bf16x8*)&Ps[row * 64 + ((cbyte ^ ((row & 7) << 4)) >> 1)];
            }
#pragma unroll
            for (int mi = 0; mi < 4; ++mi)
#pragma unroll
                for (int nj = 0; nj < 4; ++nj)
                    acc[mi][nj] = __builtin_amdgcn_mfma_f32_16x16x32_bf16(
                        af[mi], bfr[nj], acc[mi][nj], 0, 0, 0);
        }
        __syncthreads();
    }

    // epilogue: lane owns 4 consecutive d; nontemporal float4 G stores
    const int lane15 = lane & 15, lq = lane >> 4;
#pragma unroll
    for (int mi = 0; mi < 4; ++mi) {
        int dloc = wd * 64 + mi * 16 + lq * 4;
        int drow = d0 + dloc;
        float4 qv = *(const float4*)&q2cs[dloc];
#pragma unroll
        for (int nj = 0; nj < 4; ++nj) {
            int tcol = t0 + wt * 64 + nj * 16 + lane15;
            size_t rowoff = ((size_t)(b << 10) + tcol);
            uint2 h2 = nt_ld2u(&hbf[rowoff * H + drow]);
            const ushort_t* hu = (const ushort_t*)&h2;
            float4 hv = make_float4(bf2f(hu[0]), bf2f(hu[1]), bf2f(hu[2]), bf2f(hu[3]));
            f32x4 a = acc[mi][nj];
            float4 cv = make_float4(a[0], a[1], a[2], a[3]);
            size_t gp = rowoff * (4 * H) + drow;
            nt_st4(&G[gp], hv);
            nt_st4(&G[gp + H], cv);
            nt_st4(&G[gp + 2 * H], make_float4(hv.x * cv.x, hv.y * cv.y,
                                               hv.z * cv.z, hv.w * cv.w));
            nt_st4(&G[gp + 3 * H], make_float4(hv.x * qv.x, hv.y * qv.y,
                                               hv.z * qv.z, hv.w * qv.w));
        }
    }
}

extern "C" void kernel_launch(void* const* d_in, const int* in_sizes, int n_in,
                              void* d_out, int out_size, void* d_ws, size_t ws_size,
                              hipStream_t stream) {
    const float* h = (const float*)d_in[0];
    const float* u = (const float*)d_in[1];
    const float* w = (const float*)d_in[2];
    const float* bb = (const float*)d_in[3];
    float* G = (float*)d_out;

    char* p = (char*)d_ws;
    ushort_t* Sb = (ushort_t*)p; p += (size_t)B * T * J * 2;
    ushort_t* u2 = (ushort_t*)p; p += (size_t)B * J * H * 2;
    ushort_t* uT = (ushort_t*)p; p += (size_t)B * H * J * 2;
    ushort_t* hbf = (ushort_t*)p; p += (size_t)B * T * H * 2;
    float* pdot = (float*)p; p += (size_t)B * J * 16 * 4;
    float* suB = (float*)p; p += B * J * 4;
    float* pcm = (float*)p; p += (size_t)B * J * 16 * 4;
    float* pcs = (float*)p; p += (size_t)B * J * 16 * 4;
    float* Mrow = (float*)p; p += B * T * 4;
    float* qpart = (float*)p;  // B*16*H*4

    k_uprep<<<dim3(H / 64, J / 64, B), 256, 0, stream>>>(u, w, u2, uT, pdot);
    k_sured<<<dim3(B * J / 256), 256, 0, stream>>>(pdot, bb, suB);
    k_gemm1<<<dim3(512), 256, 0, stream>>>(h, u2, suB, Sb, hbf, Mrow, pcm, pcs);
    k_q2c_part<<<dim3(16, B), 256, 0, stream>>>(hbf, Mrow, qpart);
    k_gemm2g<<<dim3(2048), 256, 0, stream>>>(Sb, uT, hbf, pcm, pcs, qpart, G);
}

// Round 7
// 241.886 us; speedup vs baseline: 1.4941x; 1.4941x over previous
//
#include <hip/hip_runtime.h>
#include <cstddef>
#include <cstdint>

#define B 32
#define T 1024
#define J 128
#define H 1024

typedef unsigned short ushort_t;
typedef __attribute__((ext_vector_type(8))) short bf16x8;
typedef __attribute__((ext_vector_type(4))) float f32x4;

__device__ __forceinline__ unsigned short f2bf(float f) {
    union { float f; unsigned u; } v;
    v.f = f;
    return (unsigned short)((v.u + 0x7FFFu + ((v.u >> 16) & 1u)) >> 16);
}
__device__ __forceinline__ float bf2f(unsigned short s) {
    union { unsigned u; float f; } v;
    v.u = ((unsigned)s) << 16;
    return v.f;
}

// ---------------------------------------------------------------------------
// k_uprep: u2_bf[b,j,d] = bf16(wh[d] + wm[d]*u), uT_bf[b,d,j] = bf16(u),
// fused partial dot pdot[(b*J+j)*16 + dtile] = sum u*wu
// ---------------------------------------------------------------------------
__global__ __launch_bounds__(256) void k_uprep(const float* __restrict__ u,
                                               const float* __restrict__ w,
                                               ushort_t* __restrict__ u2,
                                               ushort_t* __restrict__ uT,
                                               float* __restrict__ pdot) {
    int b = blockIdx.z, j0 = blockIdx.y * 64, d0 = blockIdx.x * 64;
    __shared__ ushort_t tile[64][72];
    int tid = threadIdx.x;
    int jr = tid >> 2, c0 = (tid & 3) * 16;
    const float* wh = w;
    const float* wu = w + H;
    const float* wm = w + 2 * H;
    size_t src = ((size_t)(b << 7) + j0 + jr) * H + d0 + c0;
    union { ushort_t us[16]; uint4 v[2]; } o;
    float dot = 0.0f;
#pragma unroll
    for (int i = 0; i < 16; i += 4) {
        float4 x = *(const float4*)&u[src + i];
        const float* xp = &x.x;
#pragma unroll
        for (int k = 0; k < 4; ++k) {
            int d = d0 + c0 + i + k;
            float uu = xp[k];
            o.us[i + k] = f2bf(wh[d] + wm[d] * uu);
            tile[jr][c0 + i + k] = f2bf(uu);
            dot += uu * wu[d];
        }
    }
    *(uint4*)&u2[src] = o.v[0];
    *(uint4*)&u2[src + 8] = o.v[1];
    dot += __shfl_xor(dot, 1);
    dot += __shfl_xor(dot, 2);
    if ((tid & 3) == 0)
        pdot[((size_t)(b << 7) + j0 + jr) * 16 + blockIdx.x] = dot;
    __syncthreads();
    int dr = tid >> 2, jc0 = (tid & 3) * 16;
    union { ushort_t us[16]; uint4 v[2]; } t2;
#pragma unroll
    for (int i = 0; i < 16; ++i) t2.us[i] = tile[jc0 + i][dr];
    size_t dst = ((size_t)(b << 10) + d0 + dr) * J + j0 + jc0;
    *(uint4*)&uT[dst] = t2.v[0];
    *(uint4*)&uT[dst + 8] = t2.v[1];
}

// ---------------------------------------------------------------------------
// k_sured: suB[col] = sum_16 pdot[col][r] + b0
// ---------------------------------------------------------------------------
__global__ __launch_bounds__(256) void k_sured(const float* __restrict__ pdot,
                                               const float* __restrict__ bscal,
                                               float* __restrict__ suB) {
    int col = blockIdx.x * 256 + threadIdx.x;
    float s = 0.0f;
#pragma unroll
    for (int r = 0; r < 16; ++r) s += pdot[(size_t)col * 16 + r];
    suB[col] = s + bscal[0];
}

// ---------------------------------------------------------------------------
// k_gemm1: S_bf = bf16(h @ u2^T + suB); side-writes hbf = bf16(h).
// Fused Mrow + per-t-block column (max,sumexp) partials.
// XCD-swizzled: 256 blocks, 512 thr, 128x128 tile, BK=64.  (round-4 version)
// ---------------------------------------------------------------------------
__global__ __launch_bounds__(512) void k_gemm1(const float* __restrict__ h,
                                               const ushort_t* __restrict__ u2,
                                               const float* __restrict__ suB,
                                               ushort_t* __restrict__ Sb,
                                               ushort_t* __restrict__ hbf,
                                               float* __restrict__ Mrow,
                                               float* __restrict__ pcm,
                                               float* __restrict__ pcs) {
    const int lid = blockIdx.x;
    const int b = (lid & 7) * 4 + (lid >> 6);
    const int tt = (lid >> 3) & 7;
    const int t0 = tt * 128;
    __shared__ ushort_t As[128 * 64];
    __shared__ ushort_t Bs[128 * 64];
    __shared__ float rm_red[2][128];
    __shared__ float cm_red[4][128];
    __shared__ float cs_red[4][128];
    const int tid = threadIdx.x;
    const int lane = tid & 63, wid = tid >> 6;
    const int wr = wid >> 1, wc = wid & 1;

    f32x4 acc[2][4] = {};

    const int srow = wid * 8 + (lane >> 3);
    const int su_ = lane & 7;
    const int r7 = lane >> 3;

    for (int k0 = 0; k0 < H; k0 += 64) {
#pragma unroll
        for (int w = 0; w < 2; ++w) {
            int row = srow + w * 64;
            int kk = (su_ ^ r7) << 3;
            size_t hoff = ((size_t)(b << 10) + t0 + row) * H + k0 + kk;
            const float* src = h + hoff;
            float4 x = *(const float4*)src;
            float4 y = *(const float4*)(src + 4);
            union { ushort_t us[8]; uint4 v; } p;
            p.us[0] = f2bf(x.x); p.us[1] = f2bf(x.y);
            p.us[2] = f2bf(x.z); p.us[3] = f2bf(x.w);
            p.us[4] = f2bf(y.x); p.us[5] = f2bf(y.y);
            p.us[6] = f2bf(y.z); p.us[7] = f2bf(y.w);
            *(uint4*)&As[row * 64 + (su_ << 3)] = p.v;
            *(uint4*)&hbf[hoff] = p.v;  // side-product: bf16 h
        }
#pragma unroll
        for (int w = 0; w < 2; ++w) {
            int row = srow + w * 64;
            int cb = (su_ ^ r7) << 4;
            uint4 val = *(const uint4*)((const char*)u2 +
                        (((size_t)(b << 7) + row) * H + k0) * 2 + cb);
            *(uint4*)&Bs[row * 64 + (su_ << 3)] = val;
        }
        __syncthreads();
#pragma unroll
        for (int ks = 0; ks < 2; ++ks) {
            bf16x8 af[2], bfr[4];
            int cbyte = ks * 64 + ((lane >> 4) << 4);
#pragma unroll
            for (int mi = 0; mi < 2; ++mi) {
                int row = wr * 32 + mi * 16 + (lane & 15);
                af[mi] = *(const bf16x8*)&As[row * 64 + ((cbyte ^ ((row & 7) << 4)) >> 1)];
            }
#pragma unroll
            for (int nj = 0; nj < 4; ++nj) {
                int row = wc * 64 + nj * 16 + (lane & 15);
                bfr[nj] = *(const bf16x8*)&Bs[row * 64 + ((cbyte ^ ((row & 7) << 4)) >> 1)];
            }
#pragma unroll
            for (int mi = 0; mi < 2; ++mi)
#pragma unroll
                for (int nj = 0; nj < 4; ++nj)
                    acc[mi][nj] = __builtin_amdgcn_mfma_f32_16x16x32_bf16(
                        af[mi], bfr[nj], acc[mi][nj], 0, 0, 0);
        }
        __syncthreads();
    }

    const int jbase = wc * 64 + (lane & 15);
    float rowmax[2][4];
#pragma unroll
    for (int mi = 0; mi < 2; ++mi)
#pragma unroll
        for (int r = 0; r < 4; ++r) rowmax[mi][r] = -INFINITY;
    float cmv[4], csv[4];
#pragma unroll
    for (int nj = 0; nj < 4; ++nj) {
        float su_v = suB[(b << 7) + jbase + nj * 16];
        float tmp[8];
        float cm = -INFINITY;
#pragma unroll
        for (int mi = 0; mi < 2; ++mi)
#pragma unroll
            for (int r = 0; r < 4; ++r) {
                float sv = acc[mi][nj][r] + su_v;
                unsigned short sb = f2bf(sv);
                float svb = bf2f(sb);
                int t = t0 + wr * 32 + mi * 16 + ((lane >> 4) << 2) + r;
                Sb[((size_t)(b << 10) + t) * J + jbase + nj * 16] = sb;
                tmp[mi * 4 + r] = svb;
                cm = fmaxf(cm, svb);
                rowmax[mi][r] = fmaxf(rowmax[mi][r], svb);
            }
        float cs = 0.0f;
#pragma unroll
        for (int i = 0; i < 8; ++i) cs += __expf(tmp[i] - cm);
        cmv[nj] = cm;
        csv[nj] = cs;
    }
#pragma unroll
    for (int mi = 0; mi < 2; ++mi)
#pragma unroll
        for (int r = 0; r < 4; ++r) {
            float v = rowmax[mi][r];
#pragma unroll
            for (int off = 1; off < 16; off <<= 1) v = fmaxf(v, __shfl_xor(v, off));
            if ((lane & 15) == 0) {
                int row = wr * 32 + mi * 16 + ((lane >> 4) << 2) + r;
                rm_red[wc][row] = v;
            }
        }
#pragma unroll
    for (int nj = 0; nj < 4; ++nj) {
        float cm = cmv[nj], cs = csv[nj];
#pragma unroll
        for (int off = 16; off < 64; off <<= 1) {
            float om = __shfl_xor(cm, off);
            float os = __shfl_xor(cs, off);
            float nm = fmaxf(cm, om);
            cs = cs * __expf(cm - nm) + os * __expf(om - nm);
            cm = nm;
        }
        if (lane < 16) {
            cm_red[wr][wc * 64 + nj * 16 + lane] = cm;
            cs_red[wr][wc * 64 + nj * 16 + lane] = cs;
        }
    }
    __syncthreads();
    if (tid < 128) {
        Mrow[(b << 10) + t0 + tid] = fmaxf(rm_red[0][tid], rm_red[1][tid]);
    } else if (tid < 256) {
        int j = tid - 128;
        float m = cm_red[0][j], s = cs_red[0][j];
#pragma unroll
        for (int r = 1; r < 4; ++r) {
            float m2 = cm_red[r][j], s2 = cs_red[r][j];
            float nm = fmaxf(m, m2);
            s = s * __expf(m - nm) + s2 * __expf(m2 - nm);
            m = nm;
        }
        int col = (b << 7) + j;
        pcm[col * 8 + tt] = m;
        pcs[col * 8 + tt] = s;
    }
}

// ---------------------------------------------------------------------------
// k_q2c_part: self-contained bt softmax stats from Mrow, then partial
// q2c over a 64-row t-chunk reading hbf. grid (16, B), 256 thr.
// ---------------------------------------------------------------------------
__global__ __launch_bounds__(256) void k_q2c_part(const ushort_t* __restrict__ hbf,
                                                  const float* __restrict__ Mrow,
                                                  float* __restrict__ part) {
    int tc = blockIdx.x, b = blockIdx.y;
    int tid = threadIdx.x;
    __shared__ float red[256];
    __shared__ float wbt[64];
    const float* mr = Mrow + (b << 10);
    float m = fmaxf(fmaxf(mr[tid], mr[tid + 256]), fmaxf(mr[tid + 512], mr[tid + 768]));
    red[tid] = m;
    __syncthreads();
    for (int o = 128; o; o >>= 1) {
        if (tid < o) red[tid] = fmaxf(red[tid], red[tid + o]);
        __syncthreads();
    }
    m = red[0];
    __syncthreads();
    float s = 0.0f;
    for (int t = tid; t < T; t += 256) s += __expf(mr[t] - m);
    red[tid] = s;
    __syncthreads();
    for (int o = 128; o; o >>= 1) {
        if (tid < o) red[tid] += red[tid + o];
        __syncthreads();
    }
    float binv = 1.0f / red[0];
    if (tid < 64) wbt[tid] = __expf(mr[tc * 64 + tid] - m) * binv;
    __syncthreads();

    int dd = tid * 4;
    float acc0 = 0.f, acc1 = 0.f, acc2 = 0.f, acc3 = 0.f;
#pragma unroll 4
    for (int i = 0; i < 64; ++i) {
        int t = tc * 64 + i;
        uint2 v = *(const uint2*)&hbf[((size_t)(b << 10) + t) * H + dd];
        const ushort_t* us = (const ushort_t*)&v;
        float wv = wbt[i];
        acc0 += wv * bf2f(us[0]);
        acc1 += wv * bf2f(us[1]);
        acc2 += wv * bf2f(us[2]);
        acc3 += wv * bf2f(us[3]);
    }
    size_t pb = (((size_t)b * 16 + tc) << 10) + dd;
    *(float4*)&part[pb] = make_float4(acc0, acc1, acc2, acc3);
}

// ---------------------------------------------------------------------------
// k_gemm2g: prologue reduces (pcm,pcs)->cmax/cinv and qpart->q2c into LDS;
// stages P with fused softmax normalize; c2q = P @ u via MFMA (A=uT rows=d,
// B=P cols=t). NEW epilogue: stage c2q tile in LDS, write G with
// row-contiguous float4 stores (full-128B-line granularity).
// ---------------------------------------------------------------------------
__global__ __launch_bounds__(256) void k_gemm2g(const ushort_t* __restrict__ Sb,
                                                const ushort_t* __restrict__ uT,
                                                const ushort_t* __restrict__ hbf,
                                                const float* __restrict__ pcm,
                                                const float* __restrict__ pcs,
                                                const float* __restrict__ qpart,
                                                float* __restrict__ G) {
    const int lid = blockIdx.x;
    const int seq = lid >> 3;
    const int b = (lid & 7) * 4 + (seq >> 6);
    const int inner = seq & 63;
    const int d0 = (inner >> 3) * 128;
    const int t0 = (inner & 7) * 128;
    __shared__ ushort_t Ps[128 * 64];
    __shared__ ushort_t Us[128 * 64];
    __shared__ float cmaxs[128], cinvs[128], q2cs[128];
    __shared__ float cst[64 * 136];   // c2q staging: 64 t-rows x 128 d (+8 pad)
    const int tid = threadIdx.x;
    const int lane = tid & 63, wid = tid >> 6;
    const int wd = wid >> 1, wt = wid & 1;

    if (tid < 128) {
        int col = (b << 7) + tid;
        float m = -INFINITY, s = 0.0f;
#pragma unroll
        for (int r = 0; r < 8; ++r) {
            float m2 = pcm[col * 8 + r], s2 = pcs[col * 8 + r];
            float nm = fmaxf(m, m2);
            s = s * __expf(m - nm) + s2 * __expf(m2 - nm);
            m = nm;
        }
        cmaxs[tid] = m;
        cinvs[tid] = 1.0f / s;
    } else {
        int d = d0 + tid - 128;
        float a = 0.0f;
#pragma unroll
        for (int tc = 0; tc < 16; ++tc)
            a += qpart[(((size_t)b * 16 + tc) << 10) + d];
        q2cs[tid - 128] = a;
    }
    __syncthreads();

    f32x4 acc[4][4] = {};
    for (int j0 = 0; j0 < J; j0 += 64) {
#pragma unroll
        for (int w = 0; w < 4; ++w) {
            int row = w * 32 + (tid >> 3);
            int u_ = tid & 7;
            int cb = (u_ ^ ((tid >> 3) & 7)) << 4;
            uint4 va = *(const uint4*)((const char*)Sb +
                       (((size_t)(b << 10) + t0 + row) * J + j0) * 2 + cb);
            int jb = j0 + (cb >> 1);
            union { ushort_t us[8]; uint4 v; } pp;
            pp.v = va;
#pragma unroll
            for (int i = 0; i < 8; ++i)
                pp.us[i] = f2bf(__expf(bf2f(pp.us[i]) - cmaxs[jb + i]) * cinvs[jb + i]);
            *(uint4*)&Ps[row * 64 + (u_ << 3)] = pp.v;
            uint4 vb = *(const uint4*)((const char*)uT +
                       (((size_t)(b << 10) + d0 + row) * J + j0) * 2 + cb);
            *(uint4*)&Us[row * 64 + (u_ << 3)] = vb;
        }
        __syncthreads();
#pragma unroll
        for (int ks = 0; ks < 2; ++ks) {
            bf16x8 af[4], bfr[4];
            int cbyte = ks * 64 + ((lane >> 4) << 4);
#pragma unroll
            for (int mi = 0; mi < 4; ++mi) {
                int row = wd * 64 + mi * 16 + (lane & 15);
                af[mi] = *(const bf16x8*)&Us[row * 64 + ((cbyte ^ ((row & 7) << 4)) >> 1)];
            }
#pragma unroll
            for (int nj = 0; nj < 4; ++nj) {
                int row = wt * 64 + nj * 16 + (lane & 15);
                bfr[nj] = *(const bf16x8*)&Ps[row * 64 + ((cbyte ^ ((row & 7) << 4)) >> 1)];
            }
#pragma unroll
            for (int mi = 0; mi < 4; ++mi)
#pragma unroll
                for (int nj = 0; nj < 4; ++nj)
                    acc[mi][nj] = __builtin_amdgcn_mfma_f32_16x16x32_bf16(
                        af[mi], bfr[nj], acc[mi][nj], 0, 0, 0);
        }
        __syncthreads();
    }

    // epilogue: two 64-row phases; stage c2q in LDS, then fully-coalesced
    // G writes (one t-row = 512B contiguous per 32 lanes).
    const int lane15 = lane & 15, lq = lane >> 4;
#pragma unroll
    for (int th = 0; th < 2; ++th) {
        if (wt == th) {
#pragma unroll
            for (int mi = 0; mi < 4; ++mi)
#pragma unroll
                for (int nj = 0; nj < 4; ++nj) {
                    int r = nj * 16 + lane15;            // local t row 0..63
                    int c = wd * 64 + mi * 16 + lq * 4;  // local d col
                    f32x4 a = acc[mi][nj];
                    *(float4*)&cst[r * 136 + c] =
                        make_float4(a[0], a[1], a[2], a[3]);
                }
        }
        __syncthreads();
#pragma unroll
        for (int it = 0; it < 8; ++it) {
            int idx = it * 256 + tid;     // 0..2047
            int r = idx >> 5;             // 0..63
            int c4 = (idx & 31) * 4;      // 0..124
            int trow = t0 + th * 64 + r;
            int drow = d0 + c4;
            float4 cv = *(const float4*)&cst[r * 136 + c4];
            size_t rowoff = (size_t)(b << 10) + trow;
            uint2 h2 = *(const uint2*)&hbf[rowoff * H + drow];
            const ushort_t* hu = (const ushort_t*)&h2;
            float4 hv = make_float4(bf2f(hu[0]), bf2f(hu[1]), bf2f(hu[2]), bf2f(hu[3]));
            float4 qv = *(const float4*)&q2cs[c4];
            size_t gp = rowoff * (4 * H) + drow;
            *(float4*)&G[gp] = hv;
            *(float4*)&G[gp + H] = cv;
            *(float4*)&G[gp + 2 * H] = make_float4(hv.x * cv.x, hv.y * cv.y,
                                                   hv.z * cv.z, hv.w * cv.w);
            *(float4*)&G[gp + 3 * H] = make_float4(hv.x * qv.x, hv.y * qv.y,
                                                   hv.z * qv.z, hv.w * qv.w);
        }
        __syncthreads();
    }
}

extern "C" void kernel_launch(void* const* d_in, const int* in_sizes, int n_in,
                              void* d_out, int out_size, void* d_ws, size_t ws_size,
                              hipStream_t stream) {
    const float* h = (const float*)d_in[0];
    const float* u = (const float*)d_in[1];
    const float* w = (const float*)d_in[2];
    const float* bb = (const float*)d_in[3];
    float* G = (float*)d_out;

    char* p = (char*)d_ws;
    ushort_t* Sb = (ushort_t*)p; p += (size_t)B * T * J * 2;
    ushort_t* u2 = (ushort_t*)p; p += (size_t)B * J * H * 2;
    ushort_t* uT = (ushort_t*)p; p += (size_t)B * H * J * 2;
    ushort_t* hbf = (ushort_t*)p; p += (size_t)B * T * H * 2;
    float* pdot = (float*)p; p += (size_t)B * J * 16 * 4;
    float* suB = (float*)p; p += B * J * 4;
    float* pcm = (float*)p; p += (size_t)B * J * 8 * 4;
    float* pcs = (float*)p; p += (size_t)B * J * 8 * 4;
    float* Mrow = (float*)p; p += B * T * 4;
    float* qpart = (float*)p;  // B*16*H*4

    k_uprep<<<dim3(H / 64, J / 64, B), 256, 0, stream>>>(u, w, u2, uT, pdot);
    k_sured<<<dim3(B * J / 256), 256, 0, stream>>>(pdot, bb, suB);
    k_gemm1<<<dim3(256), 512, 0, stream>>>(h, u2, suB, Sb, hbf, Mrow, pcm, pcs);
    k_q2c_part<<<dim3(16, B), 256, 0, stream>>>(hbf, Mrow, qpart);
    k_gemm2g<<<dim3(2048), 256, 0, stream>>>(Sb, uT, hbf, pcm, pcs, qpart, G);
}

// Round 8
// 239.272 us; speedup vs baseline: 1.5104x; 1.0109x over previous
//
#include <hip/hip_runtime.h>
#include <cstddef>
#include <cstdint>

#define B 32
#define T 1024
#define J 128
#define H 1024

typedef unsigned short ushort_t;
typedef __attribute__((ext_vector_type(8))) short bf16x8;
typedef __attribute__((ext_vector_type(4))) float f32x4;

__device__ __forceinline__ unsigned short f2bf(float f) {
    union { float f; unsigned u; } v;
    v.f = f;
    return (unsigned short)((v.u + 0x7FFFu + ((v.u >> 16) & 1u)) >> 16);
}
__device__ __forceinline__ float bf2f(unsigned short s) {
    union { unsigned u; float f; } v;
    v.u = ((unsigned)s) << 16;
    return v.f;
}

// ---------------------------------------------------------------------------
// k_uprep: uT_bf[b,d,j] = bf16(u), fused partial dot
// pdot[(b*J+j)*16 + dtile] = sum u*wu.  (u2 is now computed inside gemm1.)
// ---------------------------------------------------------------------------
__global__ __launch_bounds__(256) void k_uprep(const float* __restrict__ u,
                                               const float* __restrict__ w,
                                               ushort_t* __restrict__ uT,
                                               float* __restrict__ pdot) {
    int b = blockIdx.z, j0 = blockIdx.y * 64, d0 = blockIdx.x * 64;
    __shared__ ushort_t tile[64][72];
    int tid = threadIdx.x;
    int jr = tid >> 2, c0 = (tid & 3) * 16;
    const float* wu = w + H;
    size_t src = ((size_t)(b << 7) + j0 + jr) * H + d0 + c0;
    float dot = 0.0f;
#pragma unroll
    for (int i = 0; i < 16; i += 4) {
        float4 x = *(const float4*)&u[src + i];
        const float* xp = &x.x;
#pragma unroll
        for (int k = 0; k < 4; ++k) {
            int d = d0 + c0 + i + k;
            float uu = xp[k];
            tile[jr][c0 + i + k] = f2bf(uu);
            dot += uu * wu[d];
        }
    }
    dot += __shfl_xor(dot, 1);
    dot += __shfl_xor(dot, 2);
    if ((tid & 3) == 0)
        pdot[((size_t)(b << 7) + j0 + jr) * 16 + blockIdx.x] = dot;
    __syncthreads();
    int dr = tid >> 2, jc0 = (tid & 3) * 16;
    union { ushort_t us[16]; uint4 v[2]; } t2;
#pragma unroll
    for (int i = 0; i < 16; ++i) t2.us[i] = tile[jc0 + i][dr];
    size_t dst = ((size_t)(b << 10) + d0 + dr) * J + j0 + jc0;
    *(uint4*)&uT[dst] = t2.v[0];
    *(uint4*)&uT[dst + 8] = t2.v[1];
}

// ---------------------------------------------------------------------------
// k_sured: suB[col] = sum_16 pdot[col][r] + b0
// ---------------------------------------------------------------------------
__global__ __launch_bounds__(256) void k_sured(const float* __restrict__ pdot,
                                               const float* __restrict__ bscal,
                                               float* __restrict__ suB) {
    int col = blockIdx.x * 256 + threadIdx.x;
    float s = 0.0f;
#pragma unroll
    for (int r = 0; r < 16; ++r) s += pdot[(size_t)col * 16 + r];
    suB[col] = s + bscal[0];
}

// ---------------------------------------------------------------------------
// k_gemm1: S_bf = bf16(h @ (wh+wm*u)^T + suB); side-writes hbf = bf16(h).
// B-operand (u2) computed ON THE FLY from u f32 (L2/L3-resident).
// Sb written via LDS bounce -> full-line coalesced stores.
// Fused Mrow + per-t-block column (max,sumexp) partials.
// XCD-swizzled: 256 blocks, 512 thr, 128x128 tile, BK=64.
// ---------------------------------------------------------------------------
__global__ __launch_bounds__(512) void k_gemm1(const float* __restrict__ h,
                                               const float* __restrict__ u,
                                               const float* __restrict__ w,
                                               const float* __restrict__ suB,
                                               ushort_t* __restrict__ Sb,
                                               ushort_t* __restrict__ hbf,
                                               float* __restrict__ Mrow,
                                               float* __restrict__ pcm,
                                               float* __restrict__ pcs) {
    const int lid = blockIdx.x;
    const int b = (lid & 7) * 4 + (lid >> 6);
    const int tt = (lid >> 3) & 7;
    const int t0 = tt * 128;
    __shared__ ushort_t As[128 * 64];
    __shared__ ushort_t Bs[128 * 64];
    __shared__ ushort_t Ss[128 * 136];
    __shared__ float rm_red[2][128];
    __shared__ float cm_red[4][128];
    __shared__ float cs_red[4][128];
    const float* wh = w;
    const float* wm = w + 2 * H;
    const int tid = threadIdx.x;
    const int lane = tid & 63, wid = tid >> 6;
    const int wr = wid >> 1, wc = wid & 1;

    f32x4 acc[2][4] = {};

    const int srow = wid * 8 + (lane >> 3);
    const int su_ = lane & 7;
    const int r7 = lane >> 3;
    const int kk = (su_ ^ r7) << 3;  // f32 element offset (A and B source)

    for (int k0 = 0; k0 < H; k0 += 64) {
        // weights for this thread's k-octet (uniform across rows)
        float4 wh0 = *(const float4*)&wh[k0 + kk];
        float4 wh1 = *(const float4*)&wh[k0 + kk + 4];
        float4 wm0 = *(const float4*)&wm[k0 + kk];
        float4 wm1 = *(const float4*)&wm[k0 + kk + 4];
        // ---- stage A: h f32 -> bf16, side-write hbf
#pragma unroll
        for (int w2 = 0; w2 < 2; ++w2) {
            int row = srow + w2 * 64;
            size_t hoff = ((size_t)(b << 10) + t0 + row) * H + k0 + kk;
            const float* src = h + hoff;
            float4 x = *(const float4*)src;
            float4 y = *(const float4*)(src + 4);
            union { ushort_t us[8]; uint4 v; } p;
            p.us[0] = f2bf(x.x); p.us[1] = f2bf(x.y);
            p.us[2] = f2bf(x.z); p.us[3] = f2bf(x.w);
            p.us[4] = f2bf(y.x); p.us[5] = f2bf(y.y);
            p.us[6] = f2bf(y.z); p.us[7] = f2bf(y.w);
            *(uint4*)&As[row * 64 + (su_ << 3)] = p.v;
            *(uint4*)&hbf[hoff] = p.v;
        }
        // ---- stage B: u2 = wh + wm*u computed on the fly (u f32 from L2/L3)
#pragma unroll
        for (int w2 = 0; w2 < 2; ++w2) {
            int row = srow + w2 * 64;
            size_t uoff = ((size_t)(b << 7) + row) * H + k0 + kk;
            float4 x = *(const float4*)&u[uoff];
            float4 y = *(const float4*)&u[uoff + 4];
            union { ushort_t us[8]; uint4 v; } p;
            p.us[0] = f2bf(wh0.x + wm0.x * x.x);
            p.us[1] = f2bf(wh0.y + wm0.y * x.y);
            p.us[2] = f2bf(wh0.z + wm0.z * x.z);
            p.us[3] = f2bf(wh0.w + wm0.w * x.w);
            p.us[4] = f2bf(wh1.x + wm1.x * y.x);
            p.us[5] = f2bf(wh1.y + wm1.y * y.y);
            p.us[6] = f2bf(wh1.z + wm1.z * y.z);
            p.us[7] = f2bf(wh1.w + wm1.w * y.w);
            *(uint4*)&Bs[row * 64 + (su_ << 3)] = p.v;
        }
        __syncthreads();
#pragma unroll
        for (int ks = 0; ks < 2; ++ks) {
            bf16x8 af[2], bfr[4];
            int cbyte = ks * 64 + ((lane >> 4) << 4);
#pragma unroll
            for (int mi = 0; mi < 2; ++mi) {
                int row = wr * 32 + mi * 16 + (lane & 15);
                af[mi] = *(const bf16x8*)&As[row * 64 + ((cbyte ^ ((row & 7) << 4)) >> 1)];
            }
#pragma unroll
            for (int nj = 0; nj < 4; ++nj) {
                int row = wc * 64 + nj * 16 + (lane & 15);
                bfr[nj] = *(const bf16x8*)&Bs[row * 64 + ((cbyte ^ ((row & 7) << 4)) >> 1)];
            }
#pragma unroll
            for (int mi = 0; mi < 2; ++mi)
#pragma unroll
                for (int nj = 0; nj < 4; ++nj)
                    acc[mi][nj] = __builtin_amdgcn_mfma_f32_16x16x32_bf16(
                        af[mi], bfr[nj], acc[mi][nj], 0, 0, 0);
        }
        __syncthreads();
    }

    // ---- epilogue: +suB, S -> LDS (Ss), row-max + column partials
    const int jbase = wc * 64 + (lane & 15);
    const int lq = lane >> 4;
    float rowmax[2][4];
#pragma unroll
    for (int mi = 0; mi < 2; ++mi)
#pragma unroll
        for (int r = 0; r < 4; ++r) rowmax[mi][r] = -INFINITY;
    float cmv[4], csv[4];
#pragma unroll
    for (int nj = 0; nj < 4; ++nj) {
        float su_v = suB[(b << 7) + jbase + nj * 16];
        float tmp[8];
        float cm = -INFINITY;
#pragma unroll
        for (int mi = 0; mi < 2; ++mi)
#pragma unroll
            for (int r = 0; r < 4; ++r) {
                float sv = acc[mi][nj][r] + su_v;
                unsigned short sb = f2bf(sv);
                float svb = bf2f(sb);
                int tloc = wr * 32 + mi * 16 + lq * 4 + r;
                Ss[tloc * 136 + jbase + nj * 16] = sb;
                tmp[mi * 4 + r] = svb;
                cm = fmaxf(cm, svb);
                rowmax[mi][r] = fmaxf(rowmax[mi][r], svb);
            }
        float cs = 0.0f;
#pragma unroll
        for (int i = 0; i < 8; ++i) cs += __expf(tmp[i] - cm);
        cmv[nj] = cm;
        csv[nj] = cs;
    }
#pragma unroll
    for (int mi = 0; mi < 2; ++mi)
#pragma unroll
        for (int r = 0; r < 4; ++r) {
            float v = rowmax[mi][r];
#pragma unroll
            for (int off = 1; off < 16; off <<= 1) v = fmaxf(v, __shfl_xor(v, off));
            if ((lane & 15) == 0) {
                int row = wr * 32 + mi * 16 + lq * 4 + r;
                rm_red[wc][row] = v;
            }
        }
#pragma unroll
    for (int nj = 0; nj < 4; ++nj) {
        float cm = cmv[nj], cs = csv[nj];
#pragma unroll
        for (int off = 16; off < 64; off <<= 1) {
            float om = __shfl_xor(cm, off);
            float os = __shfl_xor(cs, off);
            float nm = fmaxf(cm, om);
            cs = cs * __expf(cm - nm) + os * __expf(om - nm);
            cm = nm;
        }
        if (lane < 16) {
            cm_red[wr][wc * 64 + nj * 16 + lane] = cm;
            cs_red[wr][wc * 64 + nj * 16 + lane] = cs;
        }
    }
    __syncthreads();
    // coalesced Sb writeout from Ss: 128 rows x 256 B
#pragma unroll
    for (int pass = 0; pass < 4; ++pass) {
        int idx = pass * 512 + tid;      // 0..2047
        int r = idx >> 4;                // 0..127
        int c = (idx & 15) << 3;         // short offset, 16B granules
        uint4 v = *(const uint4*)&Ss[r * 136 + c];
        *(uint4*)&Sb[((size_t)(b << 10) + t0 + r) * J + c] = v;
    }
    if (tid < 128) {
        Mrow[(b << 10) + t0 + tid] = fmaxf(rm_red[0][tid], rm_red[1][tid]);
    } else if (tid < 256) {
        int j = tid - 128;
        float m = cm_red[0][j], s = cs_red[0][j];
#pragma unroll
        for (int r = 1; r < 4; ++r) {
            float m2 = cm_red[r][j], s2 = cs_red[r][j];
            float nm = fmaxf(m, m2);
            s = s * __expf(m - nm) + s2 * __expf(m2 - nm);
            m = nm;
        }
        int col = (b << 7) + j;
        pcm[col * 8 + tt] = m;
        pcs[col * 8 + tt] = s;
    }
}

// ---------------------------------------------------------------------------
// k_q2c_part: self-contained bt softmax stats from Mrow, then partial
// q2c over a 64-row t-chunk reading hbf. grid (16, B), 256 thr.
// ---------------------------------------------------------------------------
__global__ __launch_bounds__(256) void k_q2c_part(const ushort_t* __restrict__ hbf,
                                                  const float* __restrict__ Mrow,
                                                  float* __restrict__ part) {
    int tc = blockIdx.x, b = blockIdx.y;
    int tid = threadIdx.x;
    __shared__ float red[256];
    __shared__ float wbt[64];
    const float* mr = Mrow + (b << 10);
    float m = fmaxf(fmaxf(mr[tid], mr[tid + 256]), fmaxf(mr[tid + 512], mr[tid + 768]));
    red[tid] = m;
    __syncthreads();
    for (int o = 128; o; o >>= 1) {
        if (tid < o) red[tid] = fmaxf(red[tid], red[tid + o]);
        __syncthreads();
    }
    m = red[0];
    __syncthreads();
    float s = 0.0f;
    for (int t = tid; t < T; t += 256) s += __expf(mr[t] - m);
    red[tid] = s;
    __syncthreads();
    for (int o = 128; o; o >>= 1) {
        if (tid < o) red[tid] += red[tid + o];
        __syncthreads();
    }
    float binv = 1.0f / red[0];
    if (tid < 64) wbt[tid] = __expf(mr[tc * 64 + tid] - m) * binv;
    __syncthreads();

    int dd = tid * 4;
    float acc0 = 0.f, acc1 = 0.f, acc2 = 0.f, acc3 = 0.f;
#pragma unroll 4
    for (int i = 0; i < 64; ++i) {
        int t = tc * 64 + i;
        uint2 v = *(const uint2*)&hbf[((size_t)(b << 10) + t) * H + dd];
        const ushort_t* us = (const ushort_t*)&v;
        float wv = wbt[i];
        acc0 += wv * bf2f(us[0]);
        acc1 += wv * bf2f(us[1]);
        acc2 += wv * bf2f(us[2]);
        acc3 += wv * bf2f(us[3]);
    }
    size_t pb = (((size_t)b * 16 + tc) << 10) + dd;
    *(float4*)&part[pb] = make_float4(acc0, acc1, acc2, acc3);
}

// ---------------------------------------------------------------------------
// k_gemm2g: prologue reduces (pcm,pcs)->cmax/cinv and qpart->q2c into LDS;
// stages P with fused softmax normalize; c2q = P @ u via MFMA (A=uT rows=d,
// B=P cols=t). Epilogue: stage c2q tile in LDS, write G with row-contiguous
// float4 stores (full-128B-line granularity).
// ---------------------------------------------------------------------------
__global__ __launch_bounds__(256) void k_gemm2g(const ushort_t* __restrict__ Sb,
                                                const ushort_t* __restrict__ uT,
                                                const ushort_t* __restrict__ hbf,
                                                const float* __restrict__ pcm,
                                                const float* __restrict__ pcs,
                                                const float* __restrict__ qpart,
                                                float* __restrict__ G) {
    const int lid = blockIdx.x;
    const int seq = lid >> 3;
    const int b = (lid & 7) * 4 + (seq >> 6);
    const int inner = seq & 63;
    const int d0 = (inner >> 3) * 128;
    const int t0 = (inner & 7) * 128;
    __shared__ ushort_t Ps[128 * 64];
    __shared__ ushort_t Us[128 * 64];
    __shared__ float cmaxs[128], cinvs[128], q2cs[128];
    __shared__ float cst[64 * 136];
    const int tid = threadIdx.x;
    const int lane = tid & 63, wid = tid >> 6;
    const int wd = wid >> 1, wt = wid & 1;

    if (tid < 128) {
        int col = (b << 7) + tid;
        float m = -INFINITY, s = 0.0f;
#pragma unroll
        for (int r = 0; r < 8; ++r) {
            float m2 = pcm[col * 8 + r], s2 = pcs[col * 8 + r];
            float nm = fmaxf(m, m2);
            s = s * __expf(m - nm) + s2 * __expf(m2 - nm);
            m = nm;
        }
        cmaxs[tid] = m;
        cinvs[tid] = 1.0f / s;
    } else {
        int d = d0 + tid - 128;
        float a = 0.0f;
#pragma unroll
        for (int tc = 0; tc < 16; ++tc)
            a += qpart[(((size_t)b * 16 + tc) << 10) + d];
        q2cs[tid - 128] = a;
    }
    __syncthreads();

    f32x4 acc[4][4] = {};
    for (int j0 = 0; j0 < J; j0 += 64) {
#pragma unroll
        for (int w = 0; w < 4; ++w) {
            int row = w * 32 + (tid >> 3);
            int u_ = tid & 7;
            int cb = (u_ ^ ((tid >> 3) & 7)) << 4;
            uint4 va = *(const uint4*)((const char*)Sb +
                       (((size_t)(b << 10) + t0 + row) * J + j0) * 2 + cb);
            int jb = j0 + (cb >> 1);
            union { ushort_t us[8]; uint4 v; } pp;
            pp.v = va;
#pragma unroll
            for (int i = 0; i < 8; ++i)
                pp.us[i] = f2bf(__expf(bf2f(pp.us[i]) - cmaxs[jb + i]) * cinvs[jb + i]);
            *(uint4*)&Ps[row * 64 + (u_ << 3)] = pp.v;
            uint4 vb = *(const uint4*)((const char*)uT +
                       (((size_t)(b << 10) + d0 + row) * J + j0) * 2 + cb);
            *(uint4*)&Us[row * 64 + (u_ << 3)] = vb;
        }
        __syncthreads();
#pragma unroll
        for (int ks = 0; ks < 2; ++ks) {
            bf16x8 af[4], bfr[4];
            int cbyte = ks * 64 + ((lane >> 4) << 4);
#pragma unroll
            for (int mi = 0; mi < 4; ++mi) {
                int row = wd * 64 + mi * 16 + (lane & 15);
                af[mi] = *(const bf16x8*)&Us[row * 64 + ((cbyte ^ ((row & 7) << 4)) >> 1)];
            }
#pragma unroll
            for (int nj = 0; nj < 4; ++nj) {
                int row = wt * 64 + nj * 16 + (lane & 15);
                bfr[nj] = *(const bf16x8*)&Ps[row * 64 + ((cbyte ^ ((row & 7) << 4)) >> 1)];
            }
#pragma unroll
            for (int mi = 0; mi < 4; ++mi)
#pragma unroll
                for (int nj = 0; nj < 4; ++nj)
                    acc[mi][nj] = __builtin_amdgcn_mfma_f32_16x16x32_bf16(
                        af[mi], bfr[nj], acc[mi][nj], 0, 0, 0);
        }
        __syncthreads();
    }

    const int lane15 = lane & 15, lq = lane >> 4;
#pragma unroll
    for (int th = 0; th < 2; ++th) {
        if (wt == th) {
#pragma unroll
            for (int mi = 0; mi < 4; ++mi)
#pragma unroll
                for (int nj = 0; nj < 4; ++nj) {
                    int r = nj * 16 + lane15;
                    int c = wd * 64 + mi * 16 + lq * 4;
                    f32x4 a = acc[mi][nj];
                    *(float4*)&cst[r * 136 + c] =
                        make_float4(a[0], a[1], a[2], a[3]);
                }
        }
        __syncthreads();
#pragma unroll
        for (int it = 0; it < 8; ++it) {
            int idx = it * 256 + tid;
            int r = idx >> 5;
            int c4 = (idx & 31) * 4;
            int trow = t0 + th * 64 + r;
            int drow = d0 + c4;
            float4 cv = *(const float4*)&cst[r * 136 + c4];
            size_t rowoff = (size_t)(b << 10) + trow;
            uint2 h2 = *(const uint2*)&hbf[rowoff * H + drow];
            const ushort_t* hu = (const ushort_t*)&h2;
            float4 hv = make_float4(bf2f(hu[0]), bf2f(hu[1]), bf2f(hu[2]), bf2f(hu[3]));
            float4 qv = *(const float4*)&q2cs[c4];
            size_t gp = rowoff * (4 * H) + drow;
            *(float4*)&G[gp] = hv;
            *(float4*)&G[gp + H] = cv;
            *(float4*)&G[gp + 2 * H] = make_float4(hv.x * cv.x, hv.y * cv.y,
                                                   hv.z * cv.z, hv.w * cv.w);
            *(float4*)&G[gp + 3 * H] = make_float4(hv.x * qv.x, hv.y * qv.y,
                                                   hv.z * qv.z, hv.w * qv.w);
        }
        __syncthreads();
    }
}

extern "C" void kernel_launch(void* const* d_in, const int* in_sizes, int n_in,
                              void* d_out, int out_size, void* d_ws, size_t ws_size,
                              hipStream_t stream) {
    const float* h = (const float*)d_in[0];
    const float* u = (const float*)d_in[1];
    const float* w = (const float*)d_in[2];
    const float* bb = (const float*)d_in[3];
    float* G = (float*)d_out;

    char* p = (char*)d_ws;
    ushort_t* Sb = (ushort_t*)p; p += (size_t)B * T * J * 2;
    ushort_t* uT = (ushort_t*)p; p += (size_t)B * H * J * 2;
    ushort_t* hbf = (ushort_t*)p; p += (size_t)B * T * H * 2;
    float* pdot = (float*)p; p += (size_t)B * J * 16 * 4;
    float* suB = (float*)p; p += B * J * 4;
    float* pcm = (float*)p; p += (size_t)B * J * 8 * 4;
    float* pcs = (float*)p; p += (size_t)B * J * 8 * 4;
    float* Mrow = (float*)p; p += B * T * 4;
    float* qpart = (float*)p;  // B*16*H*4

    k_uprep<<<dim3(H / 64, J / 64, B), 256, 0, stream>>>(u, w, uT, pdot);
    k_sured<<<dim3(B * J / 256), 256, 0, stream>>>(pdot, bb, suB);
    k_gemm1<<<dim3(256), 512, 0, stream>>>(h, u, w, suB, Sb, hbf, Mrow, pcm, pcs);
    k_q2c_part<<<dim3(16, B), 256, 0, stream>>>(hbf, Mrow, qpart);
    k_gemm2g<<<dim3(2048), 256, 0, stream>>>(Sb, uT, hbf, pcm, pcs, qpart, G);
}